// Round 15
// baseline (64.346 us; speedup 1.0000x reference)
//
#include <hip/hip_runtime.h>
#include <math.h>

#define Bn 32
#define Ln 524288
#define NF 4

#define TPB   256               // 4 waves
#define NW    (TPB / 64)        // 4
#define CPT   18                // samples per thread (9 float2, 2-way-free LDS stride)
#define OUT   4096              // output samples per tile
#define WU    512               // warm-up samples
#define S_WG  (OUT + WU)        // 4608
#define TPR   (Ln / OUT)        // 128 tiles per row
#define NTILE 4                 // tiles per WG (double-buffered DMA pipeline)
#define NWG   (Bn * TPR / NTILE)// 1024 WGs = 4 per CU, all resident

#define SLOT4  (S_WG / 4)       // 1152 float4 slots per buffer
#define OSLOT4 (OUT / 4)        // 1024
#define WSLOT4 (WU / 4)         // 128

// ws layout (float indices)
#define COEF_OFF 0               // 20
#define POWJ_OFF 64              // j=0..5: A^(18*2^j)      (384)
#define XW1_OFF  448             // A^1152 (wave span)      (64)
#define PLM4_OFF 512             // packed PLM[l]=A^(18l): 10 grp x 64 lane x f4 (2560)
#define WSEQ_OFF 3072            // w_n = C*A^n: 18 x 8     (144)

// packed block-lower-triangular index maps (rows use cols 0..(r|1))
__device__ __forceinline__ constexpr int prow(int p) {
    return (p < 2) ? 0 : (p < 4) ? 1 : (p < 8) ? 2 : (p < 12) ? 3
         : (p < 18) ? 4 : (p < 24) ? 5 : (p < 32) ? 6 : 7;
}
__device__ __forceinline__ constexpr int pcol(int p) {
    return p - ((p < 2) ? 0 : (p < 4) ? 2 : (p < 8) ? 4 : (p < 12) ? 8
              : (p < 18) ? 12 : (p < 24) ? 18 : (p < 32) ? 24 : 32);
}

// ---------------------------------------------------------------------------
// Precompute (1 block, 64 thr) — identical math to R10 (verified 0.015625).
// ---------------------------------------------------------------------------
__global__ void precompute_k(const float* __restrict__ lr,
                             const float* __restrict__ ra,
                             const float* __restrict__ b0,
                             const float* __restrict__ b1,
                             const float* __restrict__ b2,
                             float* __restrict__ ws) {
    __shared__ double A2d[6][64];
    __shared__ float  A2f[6][64];
    __shared__ double Tw[64];
    const int t = threadIdx.x;  // 64

    if (t < NF) {
        double r   = 0.999 / (1.0 + exp(-(double)lr[t]));
        double ang = 3.14159265358979323846 / (1.0 + exp(-(double)ra[t]));
        ws[COEF_OFF + t * 5 + 0] = b0[t];
        ws[COEF_OFF + t * 5 + 1] = b1[t];
        ws[COEF_OFF + t * 5 + 2] = b2[t];
        ws[COEF_OFF + t * 5 + 3] = (float)(-2.0 * r * cos(ang));
        ws[COEF_OFF + t * 5 + 4] = (float)(r * r);
    }
    __syncthreads();

    if (t < 8) {
        double cb0[NF], cb1[NF], cb2[NF], ca1[NF], ca2[NF];
        for (int f = 0; f < NF; ++f) {
            cb0[f] = (double)ws[COEF_OFF + f * 5 + 0];
            cb1[f] = (double)ws[COEF_OFF + f * 5 + 1];
            cb2[f] = (double)ws[COEF_OFF + f * 5 + 2];
            ca1[f] = (double)ws[COEF_OFF + f * 5 + 3];
            ca2[f] = (double)ws[COEF_OFF + f * 5 + 4];
        }
        double s[8];
        for (int r = 0; r < 8; ++r) s[r] = 0.0;
        s[t] = 1.0;
        for (int n = 0; n < CPT; ++n) {
            double v = 0.0;  // zero input
            for (int f = 0; f < NF; ++f) {
                double y     = cb0[f] * v + s[2 * f];
                s[2 * f]     = cb1[f] * v - ca1[f] * y + s[2 * f + 1];
                s[2 * f + 1] = cb2[f] * v - ca2[f] * y;
                v = y;
            }
            ws[WSEQ_OFF + n * 8 + t] = (float)v;  // w_n[t]
        }
        for (int r = 0; r < 8; ++r) A2d[0][r * 8 + t] = s[r];  // col t of A^18
    }
    __syncthreads();

    A2f[0][t] = (float)A2d[0][t];
    ws[POWJ_OFF + t] = A2f[0][t];
    const int r8 = t >> 3, c8 = t & 7;
    for (int j = 1; j <= 6; ++j) {
        const double* S = A2d[j - 1];
        double acc = 0.0;
        for (int m = 0; m < 8; ++m) acc += S[r8 * 8 + m] * S[m * 8 + c8];
        Tw[t] = acc;
        __syncthreads();
        if (j <= 5) {
            A2d[j][t] = Tw[t];
            A2f[j][t] = (float)Tw[t];
            ws[POWJ_OFF + j * 64 + t] = (float)Tw[t];
        } else {
            ws[XW1_OFF + t] = (float)Tw[t];  // A^1152
        }
        __syncthreads();
    }

    // PLM[t] = A^(18*t) via binary decomposition
    float M[64];
#pragma unroll
    for (int i = 0; i < 64; ++i) M[i] = ((i >> 3) == (i & 7)) ? 1.f : 0.f;
    for (int j = 0; j < 6; ++j) {
        if ((t >> j) & 1) {
            float Tn[64];
            for (int r = 0; r < 8; ++r)
                for (int c = 0; c < 8; ++c) {
                    float acc = 0.f;
                    for (int m = 0; m < 8; ++m)
                        acc = fmaf(M[r * 8 + m], A2f[j][m * 8 + c], acc);
                    Tn[r * 8 + c] = acc;
                }
            for (int i = 0; i < 64; ++i) M[i] = Tn[i];
        }
    }
    for (int p = 0; p < 40; ++p)
        ws[PLM4_OFF + (p >> 2) * 256 + t * 4 + (p & 3)] = M[prow(p) * 8 + pcol(p)];
}

// ---------------------------------------------------------------------------
__device__ __forceinline__ void step1(float& u, float* s,
                                      const float* c0, const float* c1,
                                      const float* c2, const float* A1,
                                      const float* A2) {
#pragma unroll
    for (int f = 0; f < NF; ++f) {
        float yv     = fmaf(c0[f], u, s[2 * f]);
        s[2 * f]     = fmaf(-A1[f], yv, fmaf(c1[f], u, s[2 * f + 1]));
        s[2 * f + 1] = fmaf(-A2[f], yv, c2[f] * u);
        u = yv;
    }
}

__device__ __forceinline__ void matvec_acc_sp(float* o, const float* __restrict__ T,
                                              const float* p) {
#pragma unroll
    for (int r = 0; r < 8; ++r) {
        const int ncol = (r | 1) + 1;
#pragma unroll
        for (int c = 0; c < 8; ++c)
            if (c < ncol) o[r] = fmaf(T[r * 8 + c], p[c], o[r]);
    }
}
__device__ __forceinline__ void matvec_rep_sp(float* h, const float* __restrict__ T) {
    float tmp[8];
#pragma unroll
    for (int r = 0; r < 8; ++r) {
        const int ncol = (r | 1) + 1;
        float acc = 0.f;
#pragma unroll
        for (int c = 0; c < 8; ++c)
            if (c < ncol) acc = fmaf(T[r * 8 + c], h[c], acc);
        tmp[r] = acc;
    }
#pragma unroll
    for (int r = 0; r < 8; ++r) h[r] = tmp[r];
}

// async global->LDS DMA, 16B per lane, linear dest (wave-uniform base + lane*16)
__device__ __forceinline__ void dma16(const float4* g, float4* l) {
    __builtin_amdgcn_global_load_lds(
        (const __attribute__((address_space(1))) unsigned int*)g,
        (__attribute__((address_space(3))) unsigned int*)l,
        16, 0, 0);
}

#define BAR_LGKM() do { asm volatile("s_waitcnt lgkmcnt(0)" ::: "memory"); \
                        __builtin_amdgcn_s_barrier(); } while (0)

// ---------------------------------------------------------------------------
// One WG = 4 consecutive tiles, double-buffered global_load_lds pipeline.
// Raw barriers + counted vmcnt keep next tile's DMA in flight across compute.
// ---------------------------------------------------------------------------
__global__ __launch_bounds__(TPB, 4) void biquad_k(const float* __restrict__ x,
                                                   const float* __restrict__ ws,
                                                   float* __restrict__ y) {
    __shared__ __align__(16) float4 buf[2][SLOT4];
    __shared__ float wagg[NW * 8];
    const int t    = threadIdx.x;
    const int lane = t & 63;
    const int w    = t >> 6;

    const float4* xg4 = (const float4*)x;
    float4* yg4 = (float4*)y;

    const int g0   = blockIdx.x * NTILE;      // tiles g0..g0+3, same row
    const int row  = g0 / TPR;
    const int tp0  = g0 % TPR;
    const long rowbase = (long)row * (Ln / 4);

    const float* __restrict__ mats = ws + POWJ_OFF;
    const float* __restrict__ xw1  = ws + XW1_OFF;

    float c0[NF], c1[NF], c2[NF], A1[NF], A2[NF];
#pragma unroll
    for (int f = 0; f < NF; ++f) {
        c0[f] = ws[COEF_OFF + f * 5 + 0];
        c1[f] = ws[COEF_OFF + f * 5 + 1];
        c2[f] = ws[COEF_OFF + f * 5 + 2];
        A1[f] = ws[COEF_OFF + f * 5 + 3];
        A2[f] = ws[COEF_OFF + f * 5 + 4];
    }

    // ---- prologue: stage tile 0 into buf[0] ----
    {
        const bool skipwu = (tp0 == 0);
        const long base4 = rowbase + (long)tp0 * OSLOT4 - WSLOT4;
        if (skipwu && t < WSLOT4) buf[0][t] = make_float4(0.f, 0.f, 0.f, 0.f);
#pragma unroll
        for (int j = 0; j < 4; ++j) {
            const int n4 = j * TPB + t;
            if (!skipwu || n4 >= WSLOT4) dma16(xg4 + base4 + n4, &buf[0][n4]);
        }
        if (t < SLOT4 - 4 * TPB) {  // 128 threads: slots [1024,1152)
            const int n4 = 4 * TPB + t;
            dma16(xg4 + base4 + n4, &buf[0][n4]);
        }
    }
    asm volatile("s_waitcnt vmcnt(0)" ::: "memory");
    BAR_LGKM();

    for (int k = 0; k < NTILE; ++k) {
        const int cur  = k & 1;
        const int tpos = tp0 + k;

        // ---- issue next tile's DMA into the other buffer (stays in flight) ----
        if (k + 1 < NTILE) {
            const long nb4 = rowbase + (long)(tpos + 1) * OSLOT4 - WSLOT4;
            float4* dst = &buf[cur ^ 1][0];
#pragma unroll
            for (int j = 0; j < 4; ++j) {
                const int n4 = j * TPB + t;
                dma16(xg4 + nb4 + n4, dst + n4);
            }
            if (t < SLOT4 - 4 * TPB) {
                const int n4 = 4 * TPB + t;
                dma16(xg4 + nb4 + n4, dst + n4);
            }
        }

        float2* l2 = (float2*)&buf[cur][0];

        // ---- pass 1: preload own chunk, filter, write y0 back in place ----
        float s[8];
#pragma unroll
        for (int r = 0; r < 8; ++r) s[r] = 0.f;
        {
            float2 xr[CPT / 2];
#pragma unroll
            for (int i = 0; i < CPT / 2; ++i) xr[i] = l2[(CPT / 2) * t + i];
#pragma unroll
            for (int i = 0; i < CPT / 2; ++i) {
                float u;
                u = xr[i].x; step1(u, s, c0, c1, c2, A1, A2); xr[i].x = u;
                u = xr[i].y; step1(u, s, c0, c1, c2, A1, A2); xr[i].y = u;
            }
#pragma unroll
            for (int i = 0; i < CPT / 2; ++i) l2[(CPT / 2) * t + i] = xr[i];
        }

        // ---- intra-wave affine Kogge-Stone over 64 chunks ----
        float v8[8];
#pragma unroll
        for (int r = 0; r < 8; ++r) v8[r] = s[r];
#pragma unroll
        for (int j = 0; j < 6; ++j) {
            const int st = 1 << j;
            float p[8];
#pragma unroll
            for (int r = 0; r < 8; ++r) p[r] = __shfl_up(v8[r], st, 64);
            if (lane >= st) matvec_acc_sp(v8, mats + j * 64, p);
        }

        if (lane == 63) {
#pragma unroll
            for (int r = 0; r < 8; ++r) wagg[w * 8 + r] = v8[r];
        }
        BAR_LGKM();  // raw barrier: DMA stays in flight

        // ---- wave entry H (redundant per-thread Horner, oldest-first) ----
        float H[8];
#pragma unroll
        for (int r = 0; r < 8; ++r) H[r] = 0.f;
#pragma unroll
        for (int m = 0; m < NW - 1; ++m) {
            if (m < w) {
                matvec_rep_sp(H, xw1);
#pragma unroll
                for (int r = 0; r < 8; ++r) H[r] += wagg[m * 8 + r];
            }
        }

        // ---- delta = PLM[lane]*H + v8[lane-1] ----
        float dlt[8];
#pragma unroll
        for (int r = 0; r < 8; ++r) dlt[r] = 0.f;
        {
            const float4* plm4 = (const float4*)(ws + PLM4_OFF);
#pragma unroll
            for (int g = 0; g < 10; ++g) {
                const float4 mv = plm4[g * 64 + lane];
                dlt[prow(4 * g + 0)] = fmaf(mv.x, H[pcol(4 * g + 0)], dlt[prow(4 * g + 0)]);
                dlt[prow(4 * g + 1)] = fmaf(mv.y, H[pcol(4 * g + 1)], dlt[prow(4 * g + 1)]);
                dlt[prow(4 * g + 2)] = fmaf(mv.z, H[pcol(4 * g + 2)], dlt[prow(4 * g + 2)]);
                dlt[prow(4 * g + 3)] = fmaf(mv.w, H[pcol(4 * g + 3)], dlt[prow(4 * g + 3)]);
            }
        }
#pragma unroll
        for (int r = 0; r < 8; ++r) {
            const float pv = __shfl_up(v8[r], 1, 64);
            if (lane > 0) dlt[r] += pv;
        }

        // ---- correction: y_n = y0_n + w_n . delta (reload y0, write back) ----
        const float* __restrict__ wsq = ws + WSEQ_OFF;
#pragma unroll
        for (int i = 0; i < CPT / 2; ++i) {
            float2 v = l2[(CPT / 2) * t + i];
            float a0 = 0.f, a1 = 0.f;
#pragma unroll
            for (int kk = 0; kk < 8; ++kk) {
                a0 = fmaf(wsq[(2 * i) * 8 + kk], dlt[kk], a0);
                a1 = fmaf(wsq[(2 * i + 1) * 8 + kk], dlt[kk], a1);
            }
            v.x += a0;
            v.y += a1;
            l2[(CPT / 2) * t + i] = v;
        }
        BAR_LGKM();  // raw barrier: DMA still in flight

        // ---- coalesced store of output region ----
        const long obase4 = rowbase + (long)tpos * OSLOT4;
#pragma unroll
        for (int j = 0; j < 4; ++j) {
            const int n4 = WSLOT4 + j * TPB + t;  // [128, 1152)
            yg4[obase4 + (n4 - WSLOT4)] = buf[cur][n4];
        }

        // ---- drain next tile's DMA (allow own 4 stores in flight) ----
        if (k + 1 < NTILE) {
            asm volatile("s_waitcnt vmcnt(4)" ::: "memory");
            __builtin_amdgcn_s_barrier();
        }
    }
}

// ---------------------------------------------------------------------------
extern "C" void kernel_launch(void* const* d_in, const int* in_sizes, int n_in,
                              void* d_out, int out_size, void* d_ws, size_t ws_size,
                              hipStream_t stream) {
    const float* x  = (const float*)d_in[0];
    const float* lr = (const float*)d_in[1];
    const float* ra = (const float*)d_in[2];
    const float* b0 = (const float*)d_in[3];
    const float* b1 = (const float*)d_in[4];
    const float* b2 = (const float*)d_in[5];
    float* y  = (float*)d_out;
    float* ws = (float*)d_ws;

    precompute_k<<<dim3(1), dim3(64), 0, stream>>>(lr, ra, b0, b1, b2, ws);
    biquad_k<<<dim3(NWG), dim3(TPB), 0, stream>>>(x, ws, y);
}

// Round 16
// 59.432 us; speedup vs baseline: 1.0827x; 1.0827x over previous
//
#include <hip/hip_runtime.h>
#include <math.h>

#define Bn 32
#define Ln 524288
#define NF 4

#define TPB   256               // 4 waves
#define NW    (TPB / 64)        // 4
#define CPT   18                // samples per thread per row (9 float2)
#define OUT   4096              // output samples per tile per row
#define WU    512               // warm-up samples
#define S_WG  (OUT + WU)        // 4608 per row
#define TPR   (Ln / OUT)        // 128 tiles per row
#define NROW  2                 // rows (independent chains) per thread
#define NWG   ((Bn / NROW) * TPR)  // 2048 WGs

#define SLOT4  (S_WG / 4)       // 1152 float4 slots per row buffer
#define OSLOT4 (OUT / 4)        // 1024
#define WSLOT4 (WU / 4)         // 128

// ws layout (float indices) — identical to R10 (verified absmax 0.015625)
#define COEF_OFF 0               // 20
#define POWJ_OFF 64              // j=0..5: A^(18*2^j)      (384)
#define XW1_OFF  448             // A^1152 (wave span)      (64)
#define PLM4_OFF 512             // packed PLM[l]=A^(18l): 10 grp x 64 lane x f4 (2560)
#define WSEQ_OFF 3072            // w_n = C*A^n: 18 x 8     (144)

// packed block-lower-triangular index maps (rows use cols 0..(r|1))
__device__ __forceinline__ constexpr int prow(int p) {
    return (p < 2) ? 0 : (p < 4) ? 1 : (p < 8) ? 2 : (p < 12) ? 3
         : (p < 18) ? 4 : (p < 24) ? 5 : (p < 32) ? 6 : 7;
}
__device__ __forceinline__ constexpr int pcol(int p) {
    return p - ((p < 2) ? 0 : (p < 4) ? 2 : (p < 8) ? 4 : (p < 12) ? 8
              : (p < 18) ? 12 : (p < 24) ? 18 : (p < 32) ? 24 : 32);
}

// ---------------------------------------------------------------------------
// Precompute (1 block, 64 thr) — identical math to R10 (verified).
// ---------------------------------------------------------------------------
__global__ void precompute_k(const float* __restrict__ lr,
                             const float* __restrict__ ra,
                             const float* __restrict__ b0,
                             const float* __restrict__ b1,
                             const float* __restrict__ b2,
                             float* __restrict__ ws) {
    __shared__ double A2d[6][64];
    __shared__ float  A2f[6][64];
    __shared__ double Tw[64];
    const int t = threadIdx.x;  // 64

    if (t < NF) {
        double r   = 0.999 / (1.0 + exp(-(double)lr[t]));
        double ang = 3.14159265358979323846 / (1.0 + exp(-(double)ra[t]));
        ws[COEF_OFF + t * 5 + 0] = b0[t];
        ws[COEF_OFF + t * 5 + 1] = b1[t];
        ws[COEF_OFF + t * 5 + 2] = b2[t];
        ws[COEF_OFF + t * 5 + 3] = (float)(-2.0 * r * cos(ang));
        ws[COEF_OFF + t * 5 + 4] = (float)(r * r);
    }
    __syncthreads();

    if (t < 8) {
        double cb0[NF], cb1[NF], cb2[NF], ca1[NF], ca2[NF];
        for (int f = 0; f < NF; ++f) {
            cb0[f] = (double)ws[COEF_OFF + f * 5 + 0];
            cb1[f] = (double)ws[COEF_OFF + f * 5 + 1];
            cb2[f] = (double)ws[COEF_OFF + f * 5 + 2];
            ca1[f] = (double)ws[COEF_OFF + f * 5 + 3];
            ca2[f] = (double)ws[COEF_OFF + f * 5 + 4];
        }
        double s[8];
        for (int r = 0; r < 8; ++r) s[r] = 0.0;
        s[t] = 1.0;
        for (int n = 0; n < CPT; ++n) {
            double v = 0.0;  // zero input
            for (int f = 0; f < NF; ++f) {
                double y     = cb0[f] * v + s[2 * f];
                s[2 * f]     = cb1[f] * v - ca1[f] * y + s[2 * f + 1];
                s[2 * f + 1] = cb2[f] * v - ca2[f] * y;
                v = y;
            }
            ws[WSEQ_OFF + n * 8 + t] = (float)v;  // w_n[t]
        }
        for (int r = 0; r < 8; ++r) A2d[0][r * 8 + t] = s[r];  // col t of A^18
    }
    __syncthreads();

    A2f[0][t] = (float)A2d[0][t];
    ws[POWJ_OFF + t] = A2f[0][t];
    const int r8 = t >> 3, c8 = t & 7;
    for (int j = 1; j <= 6; ++j) {
        const double* S = A2d[j - 1];
        double acc = 0.0;
        for (int m = 0; m < 8; ++m) acc += S[r8 * 8 + m] * S[m * 8 + c8];
        Tw[t] = acc;
        __syncthreads();
        if (j <= 5) {
            A2d[j][t] = Tw[t];
            A2f[j][t] = (float)Tw[t];
            ws[POWJ_OFF + j * 64 + t] = (float)Tw[t];
        } else {
            ws[XW1_OFF + t] = (float)Tw[t];  // A^1152
        }
        __syncthreads();
    }

    // PLM[t] = A^(18*t) via binary decomposition
    float M[64];
#pragma unroll
    for (int i = 0; i < 64; ++i) M[i] = ((i >> 3) == (i & 7)) ? 1.f : 0.f;
    for (int j = 0; j < 6; ++j) {
        if ((t >> j) & 1) {
            float Tn[64];
            for (int r = 0; r < 8; ++r)
                for (int c = 0; c < 8; ++c) {
                    float acc = 0.f;
                    for (int m = 0; m < 8; ++m)
                        acc = fmaf(M[r * 8 + m], A2f[j][m * 8 + c], acc);
                    Tn[r * 8 + c] = acc;
                }
            for (int i = 0; i < 64; ++i) M[i] = Tn[i];
        }
    }
    for (int p = 0; p < 40; ++p)
        ws[PLM4_OFF + (p >> 2) * 256 + t * 4 + (p & 3)] = M[prow(p) * 8 + pcol(p)];
}

// ---------------------------------------------------------------------------
// Dual-chain filter step: two independent rows through shared coefficients.
__device__ __forceinline__ void step2(float& u0, float& u1, float* s0, float* s1,
                                      const float* c0, const float* c1,
                                      const float* c2, const float* A1,
                                      const float* A2) {
#pragma unroll
    for (int f = 0; f < NF; ++f) {
        const float yv0 = fmaf(c0[f], u0, s0[2 * f]);
        const float yv1 = fmaf(c0[f], u1, s1[2 * f]);
        s0[2 * f]     = fmaf(-A1[f], yv0, fmaf(c1[f], u0, s0[2 * f + 1]));
        s1[2 * f]     = fmaf(-A1[f], yv1, fmaf(c1[f], u1, s1[2 * f + 1]));
        s0[2 * f + 1] = fmaf(-A2[f], yv0, c2[f] * u0);
        s1[2 * f + 1] = fmaf(-A2[f], yv1, c2[f] * u1);
        u0 = yv0;
        u1 = yv1;
    }
}

// Sparse matvecs (block-lower-triangular, 40 fma); T wave-uniform -> scalar.
__device__ __forceinline__ void matvec_acc_sp(float* o, const float* __restrict__ T,
                                              const float* p) {
#pragma unroll
    for (int r = 0; r < 8; ++r) {
        const int ncol = (r | 1) + 1;
#pragma unroll
        for (int c = 0; c < 8; ++c)
            if (c < ncol) o[r] = fmaf(T[r * 8 + c], p[c], o[r]);
    }
}
__device__ __forceinline__ void matvec_rep_sp(float* h, const float* __restrict__ T) {
    float tmp[8];
#pragma unroll
    for (int r = 0; r < 8; ++r) {
        const int ncol = (r | 1) + 1;
        float acc = 0.f;
#pragma unroll
        for (int c = 0; c < 8; ++c)
            if (c < ncol) acc = fmaf(T[r * 8 + c], h[c], acc);
        tmp[r] = acc;
    }
#pragma unroll
    for (int r = 0; r < 8; ++r) h[r] = tmp[r];
}

// ---------------------------------------------------------------------------
// One WG = same 4096-sample tile position in TWO adjacent rows.
// Each thread runs two independent chains -> 2x per-wave ILP in every
// latency-bound phase (filter, scan, correction).
// ---------------------------------------------------------------------------
__global__ __launch_bounds__(TPB, 4) void biquad_k(const float* __restrict__ x,
                                                   const float* __restrict__ ws,
                                                   float* __restrict__ y) {
    __shared__ __align__(16) float4 buf[NROW][SLOT4];
    __shared__ float wagg[NROW][NW * 8];
    const int t    = threadIdx.x;
    const int lane = t & 63;
    const int w    = t >> 6;

    const int rp   = blockIdx.x / TPR;        // row pair index
    const int tpos = blockIdx.x % TPR;
    const int r0   = rp * NROW;

    const float4* xg4 = (const float4*)x;
    float4* yg4 = (float4*)y;
    const long base0 = (long)r0 * (Ln / 4) + (long)tpos * OSLOT4 - WSLOT4;
    const long base1 = base0 + (Ln / 4);

    const float* __restrict__ mats = ws + POWJ_OFF;
    const float* __restrict__ xw1  = ws + XW1_OFF;

    float c0[NF], c1[NF], c2[NF], A1[NF], A2[NF];
#pragma unroll
    for (int f = 0; f < NF; ++f) {
        c0[f] = ws[COEF_OFF + f * 5 + 0];
        c1[f] = ws[COEF_OFF + f * 5 + 1];
        c2[f] = ws[COEF_OFF + f * 5 + 2];
        A1[f] = ws[COEF_OFF + f * 5 + 3];
        A2[f] = ws[COEF_OFF + f * 5 + 4];
    }

    // ---- stage both rows -> LDS (coalesced float4, identity slots) ----
#pragma unroll
    for (int j = 0; j < 5; ++j) {
        const int n4 = j * TPB + t;
        if (n4 < SLOT4) {
            float4 v0 = make_float4(0.f, 0.f, 0.f, 0.f);
            float4 v1 = v0;
            if (tpos > 0 || n4 >= WSLOT4) {
                v0 = xg4[base0 + n4];
                v1 = xg4[base1 + n4];
            }
            buf[0][n4] = v0;
            buf[1][n4] = v1;
        }
    }
    __syncthreads();

    const float2* l20 = (const float2*)&buf[0][0];
    const float2* l21 = (const float2*)&buf[1][0];

    // ---- pass 1: dual-chain zero-state filter; y0 kept in regs ----
    float s0[8], s1[8];
#pragma unroll
    for (int r = 0; r < 8; ++r) { s0[r] = 0.f; s1[r] = 0.f; }
    float2 xr0[CPT / 2], xr1[CPT / 2];
#pragma unroll
    for (int i = 0; i < CPT / 2; ++i) {
        xr0[i] = l20[(CPT / 2) * t + i];
        xr1[i] = l21[(CPT / 2) * t + i];
    }
#pragma unroll
    for (int i = 0; i < CPT / 2; ++i) {
        float u0 = xr0[i].x, u1 = xr1[i].x;
        step2(u0, u1, s0, s1, c0, c1, c2, A1, A2);
        xr0[i].x = u0; xr1[i].x = u1;
        u0 = xr0[i].y; u1 = xr1[i].y;
        step2(u0, u1, s0, s1, c0, c1, c2, A1, A2);
        xr0[i].y = u0; xr1[i].y = u1;
    }

    // ---- dual intra-wave affine Kogge-Stone over 64 chunks ----
    float v8a[8], v8b[8];
#pragma unroll
    for (int r = 0; r < 8; ++r) { v8a[r] = s0[r]; v8b[r] = s1[r]; }
#pragma unroll
    for (int j = 0; j < 6; ++j) {
        const int st = 1 << j;
        float pa[8], pb[8];
#pragma unroll
        for (int r = 0; r < 8; ++r) {
            pa[r] = __shfl_up(v8a[r], st, 64);
            pb[r] = __shfl_up(v8b[r], st, 64);
        }
        if (lane >= st) {
            matvec_acc_sp(v8a, mats + j * 64, pa);
            matvec_acc_sp(v8b, mats + j * 64, pb);
        }
    }

    if (lane == 63) {
#pragma unroll
        for (int r = 0; r < 8; ++r) {
            wagg[0][w * 8 + r] = v8a[r];
            wagg[1][w * 8 + r] = v8b[r];
        }
    }
    __syncthreads();

    // ---- wave entry H (redundant per-thread Horner, oldest-first) ----
    float H0[8], H1[8];
#pragma unroll
    for (int r = 0; r < 8; ++r) { H0[r] = 0.f; H1[r] = 0.f; }
#pragma unroll
    for (int m = 0; m < NW - 1; ++m) {
        if (m < w) {
            matvec_rep_sp(H0, xw1);
            matvec_rep_sp(H1, xw1);
#pragma unroll
            for (int r = 0; r < 8; ++r) {
                H0[r] += wagg[0][m * 8 + r];
                H1[r] += wagg[1][m * 8 + r];
            }
        }
    }

    // ---- delta = PLM[lane]*H + v8[lane-1]; PLM loads shared by both rows ----
    float d0[8], d1[8];
#pragma unroll
    for (int r = 0; r < 8; ++r) { d0[r] = 0.f; d1[r] = 0.f; }
    {
        const float4* plm4 = (const float4*)(ws + PLM4_OFF);
#pragma unroll
        for (int g = 0; g < 10; ++g) {
            const float4 mv = plm4[g * 64 + lane];
            d0[prow(4 * g + 0)] = fmaf(mv.x, H0[pcol(4 * g + 0)], d0[prow(4 * g + 0)]);
            d1[prow(4 * g + 0)] = fmaf(mv.x, H1[pcol(4 * g + 0)], d1[prow(4 * g + 0)]);
            d0[prow(4 * g + 1)] = fmaf(mv.y, H0[pcol(4 * g + 1)], d0[prow(4 * g + 1)]);
            d1[prow(4 * g + 1)] = fmaf(mv.y, H1[pcol(4 * g + 1)], d1[prow(4 * g + 1)]);
            d0[prow(4 * g + 2)] = fmaf(mv.z, H0[pcol(4 * g + 2)], d0[prow(4 * g + 2)]);
            d1[prow(4 * g + 2)] = fmaf(mv.z, H1[pcol(4 * g + 2)], d1[prow(4 * g + 2)]);
            d0[prow(4 * g + 3)] = fmaf(mv.w, H0[pcol(4 * g + 3)], d0[prow(4 * g + 3)]);
            d1[prow(4 * g + 3)] = fmaf(mv.w, H1[pcol(4 * g + 3)], d1[prow(4 * g + 3)]);
        }
    }
#pragma unroll
    for (int r = 0; r < 8; ++r) {
        const float pa = __shfl_up(v8a[r], 1, 64);
        const float pb = __shfl_up(v8b[r], 1, 64);
        if (lane > 0) { d0[r] += pa; d1[r] += pb; }
    }

    // ---- correction: y_n = y0_n + w_n . delta (wsq loads feed 4 dots) ----
    const float* __restrict__ wsq = ws + WSEQ_OFF;
#pragma unroll
    for (int i = 0; i < CPT / 2; ++i) {
        float a0 = 0.f, a1 = 0.f, b0v = 0.f, b1v = 0.f;
#pragma unroll
        for (int k = 0; k < 8; ++k) {
            const float w0 = wsq[(2 * i) * 8 + k];
            const float w1 = wsq[(2 * i + 1) * 8 + k];
            a0  = fmaf(w0, d0[k], a0);
            b0v = fmaf(w0, d1[k], b0v);
            a1  = fmaf(w1, d0[k], a1);
            b1v = fmaf(w1, d1[k], b1v);
        }
        xr0[i].x += a0;  xr0[i].y += a1;
        xr1[i].x += b0v; xr1[i].y += b1v;
    }

    // ---- y regs -> LDS; coalesced stores for both rows ----
    {
        float2* o20 = (float2*)&buf[0][0];
        float2* o21 = (float2*)&buf[1][0];
#pragma unroll
        for (int i = 0; i < CPT / 2; ++i) {
            o20[(CPT / 2) * t + i] = xr0[i];
            o21[(CPT / 2) * t + i] = xr1[i];
        }
    }
    __syncthreads();

    const long ob0 = (long)r0 * (Ln / 4) + (long)tpos * OSLOT4;
    const long ob1 = ob0 + (Ln / 4);
#pragma unroll
    for (int j = 0; j < 4; ++j) {
        const int n4 = WSLOT4 + j * TPB + t;  // [128, 1152)
        yg4[ob0 + (n4 - WSLOT4)] = buf[0][n4];
        yg4[ob1 + (n4 - WSLOT4)] = buf[1][n4];
    }
}

// ---------------------------------------------------------------------------
extern "C" void kernel_launch(void* const* d_in, const int* in_sizes, int n_in,
                              void* d_out, int out_size, void* d_ws, size_t ws_size,
                              hipStream_t stream) {
    const float* x  = (const float*)d_in[0];
    const float* lr = (const float*)d_in[1];
    const float* ra = (const float*)d_in[2];
    const float* b0 = (const float*)d_in[3];
    const float* b1 = (const float*)d_in[4];
    const float* b2 = (const float*)d_in[5];
    float* y  = (float*)d_out;
    float* ws = (float*)d_ws;

    precompute_k<<<dim3(1), dim3(64), 0, stream>>>(lr, ra, b0, b1, b2, ws);
    biquad_k<<<dim3(NWG), dim3(TPB), 0, stream>>>(x, ws, y);
}

// Round 17
// 58.413 us; speedup vs baseline: 1.1016x; 1.0175x over previous
//
#include <hip/hip_runtime.h>
#include <math.h>

#define Bn 32
#define Ln 524288
#define NF 4

#define TPB   256               // 4 waves
#define NW    (TPB / 64)        // 4
#define CPT   18                // samples per thread (9 float2)
#define OUT   4096              // output samples per tile
#define WU    512               // warm-up samples
#define S_WG  (OUT + WU)        // 4608
#define TPR   (Ln / OUT)        // 128 tiles per row
#define NTILE 4                 // tiles per WG
#define NWG   (Bn * TPR / NTILE)// 1024 WGs = 4/CU, single generation

#define SLOT4  (S_WG / 4)       // 1152 float4 slots per buffer
#define OSLOT4 (OUT / 4)        // 1024
#define WSLOT4 (WU / 4)         // 128

// ws layout (float indices) — identical to R10 (verified absmax 0.015625)
#define COEF_OFF 0
#define POWJ_OFF 64              // j=0..5: A^(18*2^j)      (384)
#define XW1_OFF  448             // A^1152                  (64)
#define PLM4_OFF 512             // packed PLM[l]=A^(18l)   (2560)
#define WSEQ_OFF 3072            // w_n = C*A^n: 18 x 8     (144)

__device__ __forceinline__ constexpr int prow(int p) {
    return (p < 2) ? 0 : (p < 4) ? 1 : (p < 8) ? 2 : (p < 12) ? 3
         : (p < 18) ? 4 : (p < 24) ? 5 : (p < 32) ? 6 : 7;
}
__device__ __forceinline__ constexpr int pcol(int p) {
    return p - ((p < 2) ? 0 : (p < 4) ? 2 : (p < 8) ? 4 : (p < 12) ? 8
              : (p < 18) ? 12 : (p < 24) ? 18 : (p < 32) ? 24 : 32);
}

// ---------------------------------------------------------------------------
// Precompute — identical math to R10 (verified).
// ---------------------------------------------------------------------------
__global__ void precompute_k(const float* __restrict__ lr,
                             const float* __restrict__ ra,
                             const float* __restrict__ b0,
                             const float* __restrict__ b1,
                             const float* __restrict__ b2,
                             float* __restrict__ ws) {
    __shared__ double A2d[6][64];
    __shared__ float  A2f[6][64];
    __shared__ double Tw[64];
    const int t = threadIdx.x;  // 64

    if (t < NF) {
        double r   = 0.999 / (1.0 + exp(-(double)lr[t]));
        double ang = 3.14159265358979323846 / (1.0 + exp(-(double)ra[t]));
        ws[COEF_OFF + t * 5 + 0] = b0[t];
        ws[COEF_OFF + t * 5 + 1] = b1[t];
        ws[COEF_OFF + t * 5 + 2] = b2[t];
        ws[COEF_OFF + t * 5 + 3] = (float)(-2.0 * r * cos(ang));
        ws[COEF_OFF + t * 5 + 4] = (float)(r * r);
    }
    __syncthreads();

    if (t < 8) {
        double cb0[NF], cb1[NF], cb2[NF], ca1[NF], ca2[NF];
        for (int f = 0; f < NF; ++f) {
            cb0[f] = (double)ws[COEF_OFF + f * 5 + 0];
            cb1[f] = (double)ws[COEF_OFF + f * 5 + 1];
            cb2[f] = (double)ws[COEF_OFF + f * 5 + 2];
            ca1[f] = (double)ws[COEF_OFF + f * 5 + 3];
            ca2[f] = (double)ws[COEF_OFF + f * 5 + 4];
        }
        double s[8];
        for (int r = 0; r < 8; ++r) s[r] = 0.0;
        s[t] = 1.0;
        for (int n = 0; n < CPT; ++n) {
            double v = 0.0;
            for (int f = 0; f < NF; ++f) {
                double y     = cb0[f] * v + s[2 * f];
                s[2 * f]     = cb1[f] * v - ca1[f] * y + s[2 * f + 1];
                s[2 * f + 1] = cb2[f] * v - ca2[f] * y;
                v = y;
            }
            ws[WSEQ_OFF + n * 8 + t] = (float)v;
        }
        for (int r = 0; r < 8; ++r) A2d[0][r * 8 + t] = s[r];
    }
    __syncthreads();

    A2f[0][t] = (float)A2d[0][t];
    ws[POWJ_OFF + t] = A2f[0][t];
    const int r8 = t >> 3, c8 = t & 7;
    for (int j = 1; j <= 6; ++j) {
        const double* S = A2d[j - 1];
        double acc = 0.0;
        for (int m = 0; m < 8; ++m) acc += S[r8 * 8 + m] * S[m * 8 + c8];
        Tw[t] = acc;
        __syncthreads();
        if (j <= 5) {
            A2d[j][t] = Tw[t];
            A2f[j][t] = (float)Tw[t];
            ws[POWJ_OFF + j * 64 + t] = (float)Tw[t];
        } else {
            ws[XW1_OFF + t] = (float)Tw[t];
        }
        __syncthreads();
    }

    float M[64];
#pragma unroll
    for (int i = 0; i < 64; ++i) M[i] = ((i >> 3) == (i & 7)) ? 1.f : 0.f;
    for (int j = 0; j < 6; ++j) {
        if ((t >> j) & 1) {
            float Tn[64];
            for (int r = 0; r < 8; ++r)
                for (int c = 0; c < 8; ++c) {
                    float acc = 0.f;
                    for (int m = 0; m < 8; ++m)
                        acc = fmaf(M[r * 8 + m], A2f[j][m * 8 + c], acc);
                    Tn[r * 8 + c] = acc;
                }
            for (int i = 0; i < 64; ++i) M[i] = Tn[i];
        }
    }
    for (int p = 0; p < 40; ++p)
        ws[PLM4_OFF + (p >> 2) * 256 + t * 4 + (p & 3)] = M[prow(p) * 8 + pcol(p)];
}

// ---------------------------------------------------------------------------
__device__ __forceinline__ void step1(float& u, float* s,
                                      const float* c0, const float* c1,
                                      const float* c2, const float* A1,
                                      const float* A2) {
#pragma unroll
    for (int f = 0; f < NF; ++f) {
        float yv     = fmaf(c0[f], u, s[2 * f]);
        s[2 * f]     = fmaf(-A1[f], yv, fmaf(c1[f], u, s[2 * f + 1]));
        s[2 * f + 1] = fmaf(-A2[f], yv, c2[f] * u);
        u = yv;
    }
}

__device__ __forceinline__ void matvec_acc_sp(float* o, const float* __restrict__ T,
                                              const float* p) {
#pragma unroll
    for (int r = 0; r < 8; ++r) {
        const int ncol = (r | 1) + 1;
#pragma unroll
        for (int c = 0; c < 8; ++c)
            if (c < ncol) o[r] = fmaf(T[r * 8 + c], p[c], o[r]);
    }
}
__device__ __forceinline__ void matvec_rep_sp(float* h, const float* __restrict__ T) {
    float tmp[8];
#pragma unroll
    for (int r = 0; r < 8; ++r) {
        const int ncol = (r | 1) + 1;
        float acc = 0.f;
#pragma unroll
        for (int c = 0; c < 8; ++c)
            if (c < ncol) acc = fmaf(T[r * 8 + c], h[c], acc);
        tmp[r] = acc;
    }
#pragma unroll
    for (int r = 0; r < 8; ++r) h[r] = tmp[r];
}

// async global->LDS DMA, 16B/lane, linear dest
__device__ __forceinline__ void dma16(const float4* g, float4* l) {
    __builtin_amdgcn_global_load_lds(
        (const __attribute__((address_space(1))) unsigned int*)g,
        (__attribute__((address_space(3))) unsigned int*)l,
        16, 0, 0);
}

#define BAR_LGKM() do { asm volatile("s_waitcnt lgkmcnt(0)" ::: "memory"); \
                        __builtin_amdgcn_s_barrier(); } while (0)

// ---------------------------------------------------------------------------
// One WG = 4 tiles; STATICALLY-NAMED double buffers so alias analysis keeps
// the next tile's global_load_lds in flight across the compute phase.
// ---------------------------------------------------------------------------
__global__ __launch_bounds__(TPB, 4) void biquad_k(const float* __restrict__ x,
                                                   const float* __restrict__ ws,
                                                   float* __restrict__ y) {
    __shared__ __align__(16) float4 bufA[SLOT4];
    __shared__ __align__(16) float4 bufB[SLOT4];
    __shared__ float wagg[NW * 8];
    const int t    = threadIdx.x;
    const int lane = t & 63;
    const int w    = t >> 6;

    const float4* xg4 = (const float4*)x;
    float4* yg4 = (float4*)y;

    const int g0   = blockIdx.x * NTILE;      // tiles g0..g0+3, same row
    const int row  = g0 / TPR;
    const int tp0  = g0 % TPR;
    const long rowbase = (long)row * (Ln / 4);

    const float* __restrict__ mats = ws + POWJ_OFF;
    const float* __restrict__ xw1  = ws + XW1_OFF;

    float c0[NF], c1[NF], c2[NF], A1[NF], A2[NF];
#pragma unroll
    for (int f = 0; f < NF; ++f) {
        c0[f] = ws[COEF_OFF + f * 5 + 0];
        c1[f] = ws[COEF_OFF + f * 5 + 1];
        c2[f] = ws[COEF_OFF + f * 5 + 2];
        A1[f] = ws[COEF_OFF + f * 5 + 3];
        A2[f] = ws[COEF_OFF + f * 5 + 4];
    }

    // ---- prologue: stage tile 0 into bufA ----
    {
        const bool skipwu = (tp0 == 0);
        const long base4 = rowbase + (long)tp0 * OSLOT4 - WSLOT4;
        if (skipwu && t < WSLOT4) bufA[t] = make_float4(0.f, 0.f, 0.f, 0.f);
#pragma unroll
        for (int j = 0; j < 4; ++j) {
            const int n4 = j * TPB + t;
            if (!skipwu || n4 >= WSLOT4) dma16(xg4 + base4 + n4, &bufA[n4]);
        }
        if (t < SLOT4 - 4 * TPB) {
            const int n4 = 4 * TPB + t;
            dma16(xg4 + base4 + n4, &bufA[n4]);
        }
    }
    asm volatile("s_waitcnt vmcnt(0)" ::: "memory");
    BAR_LGKM();

    // ---- per-tile body; CURB/NXTB are static names (compile-time objects) ----
#define TILE_BODY(CURB, NXTB, K)                                               \
    do {                                                                       \
        const int tpos = tp0 + (K);                                           \
        if ((K) + 1 < NTILE) { /* issue next tile's DMA into NXTB */           \
            const long nb4 = rowbase + (long)(tpos + 1) * OSLOT4 - WSLOT4;     \
            _Pragma("unroll")                                                  \
            for (int j = 0; j < 4; ++j) {                                      \
                const int n4 = j * TPB + t;                                    \
                dma16(xg4 + nb4 + n4, &NXTB[n4]);                              \
            }                                                                  \
            if (t < SLOT4 - 4 * TPB) {                                         \
                const int n4 = 4 * TPB + t;                                    \
                dma16(xg4 + nb4 + n4, &NXTB[n4]);                              \
            }                                                                  \
            __builtin_amdgcn_sched_barrier(0);                                 \
        }                                                                      \
        float2* l2 = (float2*)&CURB[0];                                        \
        float s[8];                                                            \
        _Pragma("unroll")                                                      \
        for (int r = 0; r < 8; ++r) s[r] = 0.f;                                \
        float2 xr[CPT / 2];                                                    \
        _Pragma("unroll")                                                      \
        for (int i = 0; i < CPT / 2; ++i) xr[i] = l2[(CPT / 2) * t + i];       \
        _Pragma("unroll")                                                      \
        for (int i = 0; i < CPT / 2; ++i) {                                    \
            float u;                                                           \
            u = xr[i].x; step1(u, s, c0, c1, c2, A1, A2); xr[i].x = u;         \
            u = xr[i].y; step1(u, s, c0, c1, c2, A1, A2); xr[i].y = u;         \
        }                                                                      \
        float v8[8];                                                           \
        _Pragma("unroll")                                                      \
        for (int r = 0; r < 8; ++r) v8[r] = s[r];                              \
        _Pragma("unroll")                                                      \
        for (int j = 0; j < 6; ++j) {                                          \
            const int st = 1 << j;                                             \
            float p[8];                                                        \
            _Pragma("unroll")                                                  \
            for (int r = 0; r < 8; ++r) p[r] = __shfl_up(v8[r], st, 64);       \
            if (lane >= st) matvec_acc_sp(v8, mats + j * 64, p);               \
        }                                                                      \
        if (lane == 63) {                                                      \
            _Pragma("unroll")                                                  \
            for (int r = 0; r < 8; ++r) wagg[w * 8 + r] = v8[r];               \
        }                                                                      \
        BAR_LGKM();                                                            \
        float H[8];                                                            \
        _Pragma("unroll")                                                      \
        for (int r = 0; r < 8; ++r) H[r] = 0.f;                                \
        _Pragma("unroll")                                                      \
        for (int m = 0; m < NW - 1; ++m) {                                     \
            if (m < w) {                                                       \
                matvec_rep_sp(H, xw1);                                         \
                _Pragma("unroll")                                              \
                for (int r = 0; r < 8; ++r) H[r] += wagg[m * 8 + r];           \
            }                                                                  \
        }                                                                      \
        float dlt[8];                                                          \
        _Pragma("unroll")                                                      \
        for (int r = 0; r < 8; ++r) dlt[r] = 0.f;                              \
        {                                                                      \
            const float4* plm4 = (const float4*)(ws + PLM4_OFF);               \
            _Pragma("unroll")                                                  \
            for (int g = 0; g < 10; ++g) {                                     \
                const float4 mv = plm4[g * 64 + lane];                         \
                dlt[prow(4 * g + 0)] = fmaf(mv.x, H[pcol(4 * g + 0)], dlt[prow(4 * g + 0)]); \
                dlt[prow(4 * g + 1)] = fmaf(mv.y, H[pcol(4 * g + 1)], dlt[prow(4 * g + 1)]); \
                dlt[prow(4 * g + 2)] = fmaf(mv.z, H[pcol(4 * g + 2)], dlt[prow(4 * g + 2)]); \
                dlt[prow(4 * g + 3)] = fmaf(mv.w, H[pcol(4 * g + 3)], dlt[prow(4 * g + 3)]); \
            }                                                                  \
        }                                                                      \
        _Pragma("unroll")                                                      \
        for (int r = 0; r < 8; ++r) {                                          \
            const float pv = __shfl_up(v8[r], 1, 64);                          \
            if (lane > 0) dlt[r] += pv;                                        \
        }                                                                      \
        const float* __restrict__ wsq = ws + WSEQ_OFF;                         \
        _Pragma("unroll")                                                      \
        for (int i = 0; i < CPT / 2; ++i) {                                    \
            float a0 = 0.f, a1 = 0.f;                                          \
            _Pragma("unroll")                                                  \
            for (int kk = 0; kk < 8; ++kk) {                                   \
                a0 = fmaf(wsq[(2 * i) * 8 + kk], dlt[kk], a0);                 \
                a1 = fmaf(wsq[(2 * i + 1) * 8 + kk], dlt[kk], a1);             \
            }                                                                  \
            xr[i].x += a0;                                                     \
            xr[i].y += a1;                                                     \
            l2[(CPT / 2) * t + i] = xr[i];                                     \
        }                                                                      \
        BAR_LGKM();                                                            \
        const long obase4 = rowbase + (long)tpos * OSLOT4;                     \
        _Pragma("unroll")                                                      \
        for (int j = 0; j < 4; ++j) {                                          \
            const int n4 = WSLOT4 + j * TPB + t;                               \
            yg4[obase4 + (n4 - WSLOT4)] = CURB[n4];                            \
        }                                                                      \
        if ((K) + 1 < NTILE) { /* drain NXTB's DMA; own stores may fly */      \
            asm volatile("s_waitcnt vmcnt(4)" ::: "memory");                   \
            __builtin_amdgcn_s_barrier();                                      \
        }                                                                      \
    } while (0)

    TILE_BODY(bufA, bufB, 0);
    TILE_BODY(bufB, bufA, 1);
    TILE_BODY(bufA, bufB, 2);
    TILE_BODY(bufB, bufA, 3);
#undef TILE_BODY
}

// ---------------------------------------------------------------------------
extern "C" void kernel_launch(void* const* d_in, const int* in_sizes, int n_in,
                              void* d_out, int out_size, void* d_ws, size_t ws_size,
                              hipStream_t stream) {
    const float* x  = (const float*)d_in[0];
    const float* lr = (const float*)d_in[1];
    const float* ra = (const float*)d_in[2];
    const float* b0 = (const float*)d_in[3];
    const float* b1 = (const float*)d_in[4];
    const float* b2 = (const float*)d_in[5];
    float* y  = (float*)d_out;
    float* ws = (float*)d_ws;

    precompute_k<<<dim3(1), dim3(64), 0, stream>>>(lr, ra, b0, b1, b2, ws);
    biquad_k<<<dim3(NWG), dim3(TPB), 0, stream>>>(x, ws, y);
}